// Round 12
// baseline (876.983 us; speedup 1.0000x reference)
//
#include <hip/hip_runtime.h>
#include <math.h>
#include <stdint.h>

#define NG 8
#define GS 2048
#define DM 512
#define NE 64
#define CAP 32
#define NROWS (NG * GS)                       // 16384 total rows (g,s)
#define COMBINE_ELEMS (33554432ull)           // 8*2048*64*32

#define GATE_BLOCKS 256                       // 64 rows per block, 4 waves
#define N4 16777216                           // 268435456 B / 16
#define XST 68                                // staged x row stride (words)
#define TBS 21                                // transpose buffer stride (odd)

// Sacrificial-measurement repeats (all kernels idempotent): inflate each
// kernel past the ~152us fillBufferAligned band so each gets its own
// rocprof top-5 row. REMOVE NEXT ROUND.
#define ZERO_REP 3
#define GATE_REP 4
#define TOPK_REP 12

typedef float f32x4 __attribute__((ext_vector_type(4)));
typedef double f64x4 __attribute__((ext_vector_type(4)));

// ---------------------------------------------------------------------------
// JAX Threefry-2x32 (partitionable path).  [verified: rounds 1,3-5,7-11]
// ---------------------------------------------------------------------------
__device__ __forceinline__ void threefry2x32(uint32_t k0, uint32_t k1,
                                             uint32_t x0, uint32_t x1,
                                             uint32_t& o0, uint32_t& o1) {
  uint32_t ks[3] = {k0, k1, k0 ^ k1 ^ 0x1BD11BDAu};
  x0 += ks[0];
  x1 += ks[1];
  const uint32_t rot[2][4] = {{13u, 15u, 26u, 6u}, {17u, 29u, 16u, 24u}};
#pragma unroll
  for (int i = 0; i < 5; ++i) {
#pragma unroll
    for (int j = 0; j < 4; ++j) {
      uint32_t r = rot[i & 1][j];
      x0 += x1;
      x1 = (x1 << r) | (x1 >> (32u - r));
      x1 ^= x0;
    }
    x0 += ks[(i + 1) % 3];
    x1 += ks[(i + 2) % 3] + (uint32_t)(i + 1);
  }
  o0 = x0;
  o1 = x1;
}

// XLA ErfInv (f32), Giles polynomial — constants bit-match xla math.cc.
__device__ __forceinline__ float erfinv_xla(float x) {
  float w = -log1pf(-x * x);
  float p;
  if (w < 5.0f) {
    w = w - 2.5f;
    p = 2.81022636e-08f;
    p = __fmaf_rn(p, w, 3.43273939e-07f);
    p = __fmaf_rn(p, w, -3.5233877e-06f);
    p = __fmaf_rn(p, w, -4.39150654e-06f);
    p = __fmaf_rn(p, w, 0.00021858087f);
    p = __fmaf_rn(p, w, -0.00125372503f);
    p = __fmaf_rn(p, w, -0.00417768164f);
    p = __fmaf_rn(p, w, 0.246640727f);
    p = __fmaf_rn(p, w, 1.50140941f);
  } else {
    w = sqrtf(w) - 3.0f;
    p = -0.000200214257f;
    p = __fmaf_rn(p, w, 0.000100950558f);
    p = __fmaf_rn(p, w, 0.00134934322f);
    p = __fmaf_rn(p, w, -0.00367342844f);
    p = __fmaf_rn(p, w, 0.00573950773f);
    p = __fmaf_rn(p, w, -0.0076224613f);
    p = __fmaf_rn(p, w, 0.00943887047f);
    p = __fmaf_rn(p, w, 1.00167406f);
    p = __fmaf_rn(p, w, 2.83297682f);
  }
  return p * x;
}

__device__ __forceinline__ float jax_normal(uint32_t idx) {
  uint32_t o0, o1;
  threefry2x32(0u, 42u, 0u, idx, o0, o1);
  uint32_t bits = o0 ^ o1;
  float f = __uint_as_float((bits >> 9) | 0x3f800000u) - 1.0f;  // [0,1)
  const float lo = __uint_as_float(0xBF7FFFFFu);                // -0.99999994
  float v = fmaxf(lo, f * 2.0f + lo);
  return __uint_as_float(0x3FB504F3u) * erfinv_xla(v);  // sqrt(2)_f32 * erfinv
}

// ---------------------------------------------------------------------------
// Kernel 0: zero the 256 MB output (plain f32x4 stores, exact partition —
// round-11 config), repeated ZERO_REP times to surface in rocprof top-5.
// ---------------------------------------------------------------------------
__global__ __launch_bounds__(256) void zero_kernel(f32x4* __restrict__ p) {
  const int b = blockIdx.x * 1024 + threadIdx.x;  // f32x4 units
  const f32x4 z = {0.f, 0.f, 0.f, 0.f};
  for (int rep = 0; rep < ZERO_REP; ++rep) {
    asm volatile("" ::: "memory");
#pragma unroll
    for (int j = 0; j < 4; ++j) p[b + j * 256] = z;
  }
}

// ---------------------------------------------------------------------------
// Kernel 1: gate (round-10/11 internals, verified absmax 4.8828e-4), body
// repeated GATE_REP times (idempotent).
// ---------------------------------------------------------------------------
__global__ __launch_bounds__(256) void gate_kernel(
    const float* __restrict__ x,    // (NROWS, 512)
    const float* __restrict__ Wt,   // (512, 64)
    float* __restrict__ gatesT) {   // (NG*NE, GS)
  __shared__ float buf[5376];       // 21504 B: x-chunk [64][68] / tb [4][64*21]
  const int gid = blockIdx.x;         // 0..255
  const int tid = threadIdx.x;
  const int l = tid & 63;             // lane
  const int w = tid >> 6;             // wave 0..3
  const int row0b = gid * 64;         // block's first row
  const int row0 = row0b + w * 16;    // wave's first row

  const int i15 = l & 15;             // A row / B-C col position
  const int k4 = l >> 4;              // k-slot within K=4

  // --- runtime probe: which x-row does acc[*][r] hold?  [verified r7-r11]
  f64x4 dr = {0., 0., 0., 0.};
  dr = __builtin_amdgcn_mfma_f64_16x16x4f64((double)i15, 0.25, dr, 0, 0, 0);
  int perm[4];
#pragma unroll
  for (int r = 0; r < 4; ++r) perm[r] = ((int)(dr[r] + 0.5)) & 15;

  const float* xrow = &buf[(w * 16 + i15) * XST + k4];

  for (int rep = 0; rep < GATE_REP; ++rep) {
    asm volatile("" ::: "memory");
    __syncthreads();   // protect buf reuse across reps

    // K-loop over 8 chunks of 64 k-values; acc[t] = 16x16 tile
    f64x4 acc[4] = {{0., 0., 0., 0.}, {0., 0., 0., 0.},
                    {0., 0., 0., 0.}, {0., 0., 0., 0.}};
    for (int ck = 0; ck < 8; ++ck) {
      for (int i = tid; i < 1024; i += 256) {
        const int r = i >> 4, c = (i & 15) << 2;
        *(f32x4*)&buf[r * XST + c] =
            *(const f32x4*)&x[(size_t)(row0b + r) * DM + (ck << 6) + c];
      }
      __syncthreads();
#pragma unroll
      for (int kkl = 0; kkl < 16; ++kkl) {
        const double a = (double)xrow[kkl * 4];
        const int kk = (ck << 4) + kkl;
        const float* wrow = Wt + ((kk << 2) + k4) * NE + i15;
#pragma unroll
        for (int t = 0; t < 4; ++t) {
          const double b = (double)wrow[16 * t];
          acc[t] = __builtin_amdgcn_mfma_f64_16x16x4f64(a, b, acc[t], 0, 0, 0);
        }
      }
      __syncthreads();
    }

    // noise + fp64 softmax. acc[t][r] = logits[row0+perm[r]][e=16t+i15].
    float gatef[4][4];  // [t][r]
#pragma unroll
    for (int r = 0; r < 4; ++r) {
      const int row = row0 + perm[r];
      double v[4];
      double m = -1.0e300;
#pragma unroll
      for (int t = 0; t < 4; ++t) {
        const float logit = (float)acc[t][r];
        const float noised =
            logit + 0.015625f * jax_normal((uint32_t)(row * NE + 16 * t + i15));
        v[t] = (double)noised;
        m = fmax(m, v[t]);
      }
#pragma unroll
      for (int off = 1; off < 16; off <<= 1) m = fmax(m, __shfl_xor(m, off, 64));
      double s = 0.0;
#pragma unroll
      for (int t = 0; t < 4; ++t) {
        v[t] = exp(v[t] - m);
        s += v[t];
      }
#pragma unroll
      for (int off = 1; off < 16; off <<= 1) s += __shfl_xor(s, off, 64);
#pragma unroll
      for (int t = 0; t < 4; ++t) gatef[t][r] = (float)(v[t] / s);
    }

    // per-wave LDS transpose (buf reused; x-chunk dead after barrier above).
    float* tb = buf + w * (NE * TBS);
#pragma unroll
    for (int t = 0; t < 4; ++t)
#pragma unroll
      for (int r = 0; r < 4; ++r)
        tb[(16 * t + i15) * TBS + perm[r]] = gatef[t][r];
    __syncthreads();

    const int g = row0 >> 11;           // group
    const int s0 = row0 & (GS - 1);     // first s of this wave's 16
    float* drow = gatesT + ((size_t)(g * NE + l)) * GS + s0;
#pragma unroll
    for (int c = 0; c < 4; ++c) {
      f32x4 o;
#pragma unroll
      for (int i = 0; i < 4; ++i) o[i] = tb[l * TBS + 4 * c + i];
      *(f32x4*)&drow[4 * c] = o;
    }
  }
}

// ---------------------------------------------------------------------------
// Kernel 2: topk (round-4 internals, verified), repeated TOPK_REP times.
// ---------------------------------------------------------------------------
__global__ __launch_bounds__(64) void topk_kernel(
    const float* __restrict__ gatesT,  // (NG*NE, GS)
    float* __restrict__ out) {         // combine ++ dispatch
  const int ge = blockIdx.x;  // == g*64 + e
  const int g = ge >> 6;
  const int e = ge & 63;
  const int lane = threadIdx.x;
  const float* base = gatesT + (size_t)ge * GS;
  float* combine = out;                   // (G,S,E,C)
  float* dispatch = out + COMBINE_ELEMS;  // (G,E,C,S)

  for (int rep = 0; rep < TOPK_REP; ++rep) {
    asm volatile("" ::: "memory");
    float v[32];
#pragma unroll
    for (int k = 0; k < 8; ++k) {
      const f32x4 t = *(const f32x4*)(base + k * 256 + lane * 4);
#pragma unroll
      for (int i = 0; i < 4; ++i) v[k * 4 + i] = t[i];
    }

    float my_v = 0.0f;
    int my_s = 0;

    for (int c = 0; c < CAP; ++c) {
      float bv = -1.0f;  // gates are strictly positive
      int bj = 0;
#pragma unroll
      for (int j = 0; j < 32; ++j) {
        const bool better = v[j] > bv;
        bv = better ? v[j] : bv;
        bj = better ? j : bj;
      }
      int bs = (bj >> 2) * 256 + lane * 4 + (bj & 3);
#pragma unroll
      for (int off = 1; off < 64; off <<= 1) {
        const float ov = __shfl_xor(bv, off, 64);
        const int os = __shfl_xor(bs, off, 64);
        if (ov > bv || (ov == bv && os < bs)) { bv = ov; bs = os; }
      }
      const bool owner = (lane == ((bs >> 2) & 63));
      const int jj = ((bs >> 8) << 2) | (bs & 3);
#pragma unroll
      for (int j = 0; j < 32; ++j) v[j] = (owner && j == jj) ? -1.0f : v[j];
      if (lane == c) { my_v = bv; my_s = bs; }
    }

    if (lane < CAP) {
      combine[(((size_t)(g * GS + my_s)) * NE + e) * CAP + lane] = my_v;
      dispatch[(((size_t)(g * NE + e)) * CAP + lane) * GS + my_s] = 1.0f;
    }
  }
}

extern "C" void kernel_launch(void* const* d_in, const int* in_sizes, int n_in,
                              void* d_out, int out_size, void* d_ws,
                              size_t ws_size, hipStream_t stream) {
  (void)in_sizes; (void)n_in; (void)ws_size; (void)out_size;
  const float* x = (const float*)d_in[0];   // (8,2048,512) f32
  const float* Wt = (const float*)d_in[1];  // (512,64) f32
  float* out = (float*)d_out;
  float* gatesT = (float*)d_ws;             // (512, 2048) f32 = 4 MB scratch

  zero_kernel<<<N4 / 1024, 256, 0, stream>>>((f32x4*)out);
  gate_kernel<<<GATE_BLOCKS, 256, 0, stream>>>(x, Wt, gatesT);
  topk_kernel<<<NG * NE, 64, 0, stream>>>(gatesT, out);
}

// Round 13
// 118.112 us; speedup vs baseline: 7.4250x; 7.4250x over previous
//
#include <hip/hip_runtime.h>
#include <math.h>
#include <stdint.h>

#define NG 8
#define GS 2048
#define DM 512
#define NE 64
#define CAP 32
#define NROWS (NG * GS)                       // 16384 total rows (g,s)
#define COMBINE_ELEMS (33554432ull)           // 8*2048*64*32

#define N4 16777216                           // 268435456 B / 16
#define GATE_BLOCKS 512                       // 32 rows per block, 2 waves
#define XST 516                               // staged x row stride (words)
#define TBS 21                                // transpose buffer stride (odd)

typedef float f32x4 __attribute__((ext_vector_type(4)));
typedef double f64x4 __attribute__((ext_vector_type(4)));
typedef unsigned long long u64;

// ---------------------------------------------------------------------------
// JAX Threefry-2x32 (partitionable path).  [verified: rounds 1,3-5,7-12]
// ---------------------------------------------------------------------------
__device__ __forceinline__ void threefry2x32(uint32_t k0, uint32_t k1,
                                             uint32_t x0, uint32_t x1,
                                             uint32_t& o0, uint32_t& o1) {
  uint32_t ks[3] = {k0, k1, k0 ^ k1 ^ 0x1BD11BDAu};
  x0 += ks[0];
  x1 += ks[1];
  const uint32_t rot[2][4] = {{13u, 15u, 26u, 6u}, {17u, 29u, 16u, 24u}};
#pragma unroll
  for (int i = 0; i < 5; ++i) {
#pragma unroll
    for (int j = 0; j < 4; ++j) {
      uint32_t r = rot[i & 1][j];
      x0 += x1;
      x1 = (x1 << r) | (x1 >> (32u - r));
      x1 ^= x0;
    }
    x0 += ks[(i + 1) % 3];
    x1 += ks[(i + 2) % 3] + (uint32_t)(i + 1);
  }
  o0 = x0;
  o1 = x1;
}

// XLA ErfInv (f32), Giles polynomial — constants bit-match xla math.cc.
__device__ __forceinline__ float erfinv_xla(float x) {
  float w = -log1pf(-x * x);
  float p;
  if (w < 5.0f) {
    w = w - 2.5f;
    p = 2.81022636e-08f;
    p = __fmaf_rn(p, w, 3.43273939e-07f);
    p = __fmaf_rn(p, w, -3.5233877e-06f);
    p = __fmaf_rn(p, w, -4.39150654e-06f);
    p = __fmaf_rn(p, w, 0.00021858087f);
    p = __fmaf_rn(p, w, -0.00125372503f);
    p = __fmaf_rn(p, w, -0.00417768164f);
    p = __fmaf_rn(p, w, 0.246640727f);
    p = __fmaf_rn(p, w, 1.50140941f);
  } else {
    w = sqrtf(w) - 3.0f;
    p = -0.000200214257f;
    p = __fmaf_rn(p, w, 0.000100950558f);
    p = __fmaf_rn(p, w, 0.00134934322f);
    p = __fmaf_rn(p, w, -0.00367342844f);
    p = __fmaf_rn(p, w, 0.00573950773f);
    p = __fmaf_rn(p, w, -0.0076224613f);
    p = __fmaf_rn(p, w, 0.00943887047f);
    p = __fmaf_rn(p, w, 1.00167406f);
    p = __fmaf_rn(p, w, 2.83297682f);
  }
  return p * x;
}

__device__ __forceinline__ float jax_normal(uint32_t idx) {
  uint32_t o0, o1;
  threefry2x32(0u, 42u, 0u, idx, o0, o1);
  uint32_t bits = o0 ^ o1;
  float f = __uint_as_float((bits >> 9) | 0x3f800000u) - 1.0f;  // [0,1)
  const float lo = __uint_as_float(0xBF7FFFFFu);                // -0.99999994
  float v = fmaxf(lo, f * 2.0f + lo);
  return __uint_as_float(0x3FB504F3u) * erfinv_xla(v);  // sqrt(2)_f32 * erfinv
}

// ---------------------------------------------------------------------------
// Kernel 0: zero the 256 MB output. Round-11 config (plain f32x4 stores,
// exact partition) — measured ~45 us, near the ~43 us HBM write floor.
// ---------------------------------------------------------------------------
__global__ __launch_bounds__(256) void zero_kernel(f32x4* __restrict__ p) {
  const int b = blockIdx.x * 1024 + threadIdx.x;  // f32x4 units
  const f32x4 z = {0.f, 0.f, 0.f, 0.f};
#pragma unroll
  for (int j = 0; j < 4; ++j) p[b + j * 256] = z;
}

// ---------------------------------------------------------------------------
// Kernel 1: gate. ROUND-13 CHANGE: single-stage staging — 512 blocks x 2
// waves, whole 32x512 x-tile staged once (66 KB LDS, 1 barrier) instead of
// 8 chunks x 2 barriers (round-12 measurement: ~37 us of staging stalls on
// ~13 us of MFMA). K-loop accumulation order IDENTICAL -> bit-identical
// gates. MFMA D-layout via runtime marker probe [verified r7-r12].
// ---------------------------------------------------------------------------
__global__ __launch_bounds__(128) void gate_kernel(
    const float* __restrict__ x,    // (NROWS, 512)
    const float* __restrict__ Wt,   // (512, 64)
    float* __restrict__ gatesT) {   // (NG*NE, GS)
  __shared__ float xs[32 * XST];    // 66048 B -> 2 blocks/CU
  const int gid = blockIdx.x;         // 0..511
  const int tid = threadIdx.x;
  const int l = tid & 63;             // lane
  const int w = tid >> 6;             // wave 0..1
  const int row0b = gid * 32;         // block's first row
  const int row0 = row0b + w * 16;    // wave's first row

  const int i15 = l & 15;             // A row / B-C col position
  const int k4 = l >> 4;              // k-slot within K=4

  // --- runtime probe: which x-row does acc[*][r] hold?  [verified r7-r12]
  f64x4 dr = {0., 0., 0., 0.};
  dr = __builtin_amdgcn_mfma_f64_16x16x4f64((double)i15, 0.25, dr, 0, 0, 0);
  int perm[4];
#pragma unroll
  for (int r = 0; r < 4; ++r) perm[r] = ((int)(dr[r] + 0.5)) & 15;

  // stage the whole 32x512 tile: 4096 f32x4 / 128 threads = 32 per thread,
  // all issued before the single barrier (fully pipelined).
#pragma unroll 8
  for (int i = tid; i < 4096; i += 128) {
    const int r = i >> 7, c = (i & 127) << 2;
    *(f32x4*)&xs[r * XST + c] =
        *(const f32x4*)&x[(size_t)(row0b + r) * DM + c];
  }
  __syncthreads();

  // K-loop: 128 steps of K=4, same order as rounds 9-12 (bit-identical).
  f64x4 acc[4] = {{0., 0., 0., 0.}, {0., 0., 0., 0.},
                  {0., 0., 0., 0.}, {0., 0., 0., 0.}};
  const float* xrow = &xs[(w * 16 + i15) * XST + k4];
#pragma unroll 4
  for (int kk = 0; kk < 128; ++kk) {
    const double a = (double)xrow[kk * 4];
    const float* wrow = Wt + ((kk << 2) + k4) * NE + i15;
#pragma unroll
    for (int t = 0; t < 4; ++t) {
      const double b = (double)wrow[16 * t];
      acc[t] = __builtin_amdgcn_mfma_f64_16x16x4f64(a, b, acc[t], 0, 0, 0);
    }
  }

  // noise + fp64 softmax. acc[t][r] = logits[row0+perm[r]][e=16t+i15].
  float gatef[4][4];  // [t][r]
#pragma unroll
  for (int r = 0; r < 4; ++r) {
    const int row = row0 + perm[r];
    double v[4];
    double m = -1.0e300;
#pragma unroll
    for (int t = 0; t < 4; ++t) {
      const float logit = (float)acc[t][r];
      const float noised =
          logit + 0.015625f * jax_normal((uint32_t)(row * NE + 16 * t + i15));
      v[t] = (double)noised;
      m = fmax(m, v[t]);
    }
#pragma unroll
    for (int off = 1; off < 16; off <<= 1) m = fmax(m, __shfl_xor(m, off, 64));
    double s = 0.0;
#pragma unroll
    for (int t = 0; t < 4; ++t) {
      v[t] = exp(v[t] - m);
      s += v[t];
    }
#pragma unroll
    for (int off = 1; off < 16; off <<= 1) s += __shfl_xor(s, off, 64);
#pragma unroll
    for (int t = 0; t < 4; ++t) gatef[t][r] = (float)(v[t] / s);
  }

  // per-wave LDS transpose into this wave's own (dead) x-slice; wave w only
  // ever read rows [16w,16w+16), so no cross-wave hazard, no barrier.
  float* tb = xs + w * (NE * TBS);
#pragma unroll
  for (int t = 0; t < 4; ++t)
#pragma unroll
    for (int r = 0; r < 4; ++r)
      tb[(16 * t + i15) * TBS + perm[r]] = gatef[t][r];

  const int g = row0 >> 11;           // group
  const int s0 = row0 & (GS - 1);     // first s of this wave's 16
  float* drow = gatesT + ((size_t)(g * NE + l)) * GS + s0;  // lane l -> expert l
#pragma unroll
  for (int c = 0; c < 4; ++c) {
    f32x4 o;
#pragma unroll
    for (int i = 0; i < 4; ++i) o[i] = tb[l * TBS + 4 * c + i];
    *(f32x4*)&drow[4 * c] = o;
  }
}

// ---------------------------------------------------------------------------
// Kernel 2: topk. ROUND-13 REWRITE: bitonic merge-prune (round-12
// measurement: the old 32-round iterative argmax was 40 us of serial
// shuffle-latency). Keys: u64 (vbits<<32)|(2047-s): softmax v>0 so float
// bits are order-monotone; ties -> smaller s = larger key (= lax.top_k
// min-index tie-break). Per lane: bitonic-sort own 32 ASC; 6 butterfly
// levels of {fetch partner reversed (32 independent u64 shfl), elementwise
// max (= top-32 of union), 80-CE bitonic clean}. All register indices
// static (rule #20). After level 6 all lanes hold the global top-32 sorted.
// ---------------------------------------------------------------------------
__global__ __launch_bounds__(64) void topk_kernel(
    const float* __restrict__ gatesT,  // (NG*NE, GS)
    float* __restrict__ out) {         // combine ++ dispatch
  const int ge = blockIdx.x;  // == g*64 + e
  const int g = ge >> 6;
  const int e = ge & 63;
  const int lane = threadIdx.x;

  const float* base = gatesT + (size_t)ge * GS;
  u64 K[32];
#pragma unroll
  for (int k = 0; k < 8; ++k) {
    const f32x4 t = *(const f32x4*)(base + k * 256 + lane * 4);
#pragma unroll
    for (int i = 0; i < 4; ++i) {
      const int s = k * 256 + lane * 4 + i;
      K[k * 4 + i] = ((u64)__float_as_uint(t[i]) << 32) | (u64)(2047 - s);
    }
  }

  // ---- per-lane bitonic sort of 32 keys, ascending ----
#pragma unroll
  for (int k = 2; k <= 32; k <<= 1) {
#pragma unroll
    for (int d = k >> 1; d > 0; d >>= 1) {
#pragma unroll
      for (int j = 0; j < 32; ++j) {
        const int ixj = j ^ d;
        if (ixj > j) {
          const bool asc = ((j & k) == 0);
          const u64 a = K[j], b = K[ixj];
          const bool sw = asc ? (a > b) : (a < b);
          K[j] = sw ? b : a;
          K[ixj] = sw ? a : b;
        }
      }
    }
  }

  // ---- 6 butterfly merge-prune levels ----
#pragma unroll
  for (int m = 1; m < 64; m <<= 1) {
    u64 tmp[32];
#pragma unroll
    for (int j = 0; j < 32; ++j) tmp[j] = __shfl_xor(K[31 - j], m, 64);
#pragma unroll
    for (int j = 0; j < 32; ++j) K[j] = (K[j] > tmp[j]) ? K[j] : tmp[j];
    // bitonic clean to ascending
#pragma unroll
    for (int d = 16; d > 0; d >>= 1) {
#pragma unroll
      for (int j = 0; j < 32; ++j) {
        if ((j & d) == 0) {
          const u64 a = K[j], b = K[j | d];
          const bool sw = (a > b);
          K[j] = sw ? b : a;
          K[j | d] = sw ? a : b;
        }
      }
    }
  }

  // ---- emit: c-th pick = K[31-c]; all lanes hold identical lists ----
  float* combine = out;                   // (G,S,E,C)
  float* dispatch = out + COMBINE_ELEMS;  // (G,E,C,S)
#pragma unroll
  for (int c = 0; c < CAP; ++c) {
    if (lane == c) {
      const u64 key = K[31 - c];
      const float v = __uint_as_float((uint32_t)(key >> 32));
      const int s = 2047 - (int)(key & 0x7FFull);
      combine[(((size_t)(g * GS + s)) * NE + e) * CAP + c] = v;
      dispatch[(((size_t)(g * NE + e)) * CAP + c) * GS + s] = 1.0f;
    }
  }
}

extern "C" void kernel_launch(void* const* d_in, const int* in_sizes, int n_in,
                              void* d_out, int out_size, void* d_ws,
                              size_t ws_size, hipStream_t stream) {
  (void)in_sizes; (void)n_in; (void)ws_size; (void)out_size;
  const float* x = (const float*)d_in[0];   // (8,2048,512) f32
  const float* Wt = (const float*)d_in[1];  // (512,64) f32
  float* out = (float*)d_out;
  float* gatesT = (float*)d_ws;             // (512, 2048) f32 = 4 MB scratch

  zero_kernel<<<N4 / 1024, 256, 0, stream>>>((f32x4*)out);
  gate_kernel<<<GATE_BLOCKS, 128, 0, stream>>>(x, Wt, gatesT);
  topk_kernel<<<NG * NE, 64, 0, stream>>>(gatesT, out);
}